// Round 9
// baseline (777.100 us; speedup 1.0000x reference)
//
#include <hip/hip_runtime.h>
#include <math.h>

#define NN 100000
#define DH 128
#define DOUT 64
#define NWIN 8
#define WIN 12500   // NN / NWIN

typedef __attribute__((ext_vector_type(8))) short bf16x8;
typedef __attribute__((ext_vector_type(4))) float f32x4;
typedef unsigned short ushort_t;

__device__ __forceinline__ short f2bf(float f) {
  unsigned u = __float_as_uint(f);
  unsigned r = (u + 0x7fffu + ((u >> 16) & 1u)) >> 16;
  return (short)r;
}
__device__ __forceinline__ float bf2f(short b) {
  return __uint_as_float(((unsigned)(unsigned short)b) << 16);
}

// ---------------------------------------------------------------------------
// Edge-index dtype detector (int64 reference vs int32 harness doc).
// ---------------------------------------------------------------------------
__global__ __launch_bounds__(256) void detect_kernel(const int* __restrict__ ei, int E,
                                                     int* __restrict__ flag) {
  const long long* e64 = (const long long*)ei;
  int lim = E < 1024 ? E : 1024;
  int ok = 1;
  for (int i = threadIdx.x; i < lim; i += 256) {
    long long v = e64[i];
    if (v < 0 || v >= NN) ok = 0;
  }
  __shared__ int s_ok;
  if (threadIdx.x == 0) s_ok = 1;
  __syncthreads();
  if (!ok) atomicAnd(&s_ok, 0);
  __syncthreads();
  if (threadIdx.x == 0) *flag = s_ok;
}

__device__ __forceinline__ int edge_at(const int* __restrict__ ei, int is64, size_t pos) {
  return is64 ? (int)(((const long long*)ei)[pos]) : ei[pos];
}

// ---------------------------------------------------------------------------
// x (fp32) -> x_bf16, 8 elems/thread.
// ---------------------------------------------------------------------------
__global__ __launch_bounds__(256) void convx_kernel(const float* __restrict__ x,
                                                    ushort_t* __restrict__ xb) {
  size_t i = ((size_t)blockIdx.x * 256 + threadIdx.x) * 8;
  if (i >= (size_t)NN * DH) return;
  float4 f0 = ((const float4*)(x + i))[0];
  float4 f1 = ((const float4*)(x + i))[1];
  bf16x8 o;
  o[0] = f2bf(f0.x); o[1] = f2bf(f0.y); o[2] = f2bf(f0.z); o[3] = f2bf(f0.w);
  o[4] = f2bf(f1.x); o[5] = f2bf(f1.y); o[6] = f2bf(f1.z); o[7] = f2bf(f1.w);
  *(bf16x8*)(xb + i) = o;
}

// ---------------------------------------------------------------------------
// One pass over edges: pack to int2 {src,dst} AND build degree histogram.
// ---------------------------------------------------------------------------
__global__ __launch_bounds__(256) void convert_deg_kernel(const int* __restrict__ ei, int E,
                                                          const int* __restrict__ flag,
                                                          int2* __restrict__ edges,
                                                          int* __restrict__ degi) {
  int e = blockIdx.x * 256 + threadIdx.x;
  if (e >= E) return;
  int is64 = *flag;
  int src = edge_at(ei, is64, (size_t)e);
  int dst = edge_at(ei, is64, (size_t)E + e);
  edges[e] = make_int2(src, dst);
  atomicAdd(&degi[dst], 1);
}

// ---------------------------------------------------------------------------
// Exclusive scan of degi -> row_ptr. Single block, 1024 thr x 4 elems/thr.
// ---------------------------------------------------------------------------
__global__ __launch_bounds__(1024) void scan_kernel(const int* __restrict__ degi,
                                                    int* __restrict__ row_ptr) {
  __shared__ int warp_sums[16];
  __shared__ int s_offset;
  int lane = threadIdx.x & 63;
  int wid = threadIdx.x >> 6;
  if (threadIdx.x == 0) s_offset = 0;
  __syncthreads();
  for (int base = 0; base < NN; base += 4096) {
    int i0 = base + threadIdx.x * 4;
    int v0 = (i0 + 0 < NN) ? degi[i0 + 0] : 0;
    int v1 = (i0 + 1 < NN) ? degi[i0 + 1] : 0;
    int v2 = (i0 + 2 < NN) ? degi[i0 + 2] : 0;
    int v3 = (i0 + 3 < NN) ? degi[i0 + 3] : 0;
    int tot = v0 + v1 + v2 + v3;
    int sv = tot;
#pragma unroll
    for (int o = 1; o < 64; o <<= 1) {
      int t = __shfl_up(sv, o, 64);
      if (lane >= o) sv += t;
    }
    if (lane == 63) warp_sums[wid] = sv;
    __syncthreads();
    if (wid == 0 && lane < 16) {
      int ws = warp_sums[lane];
#pragma unroll
      for (int o = 1; o < 16; o <<= 1) {
        int t = __shfl_up(ws, o, 16);
        if (lane >= o) ws += t;
      }
      warp_sums[lane] = ws;
    }
    __syncthreads();
    int wave_off = (wid == 0) ? 0 : warp_sums[wid - 1];
    int excl = s_offset + wave_off + sv - tot;
    if (i0 + 0 < NN) row_ptr[i0 + 0] = excl;
    if (i0 + 1 < NN) row_ptr[i0 + 1] = excl + v0;
    if (i0 + 2 < NN) row_ptr[i0 + 2] = excl + v0 + v1;
    if (i0 + 3 < NN) row_ptr[i0 + 3] = excl + v0 + v1 + v2;
    __syncthreads();
    if (threadIdx.x == 1023) s_offset = excl + tot;
    __syncthreads();
  }
}

// ---------------------------------------------------------------------------
// Snapshot window bases from row_ptr (separate dispatch: no intra-block
// global-coherence games). qbase[p] = first col index of window p.
// qcur = bin write cursors; claim = fill chunk-claim counters.
// ---------------------------------------------------------------------------
__global__ __launch_bounds__(64) void qinit_kernel(const int* __restrict__ row_ptr, int E,
                                                   int* __restrict__ qbase,
                                                   int* __restrict__ qcur,
                                                   int* __restrict__ claim) {
  int t = threadIdx.x;
  if (t < NWIN) {
    int b = row_ptr[t * WIN];
    qbase[t] = b;
    qcur[t] = b;
    claim[t] = 0;
  }
  if (t == NWIN) qbase[NWIN] = E;
}

// ---------------------------------------------------------------------------
// Bin edges by dst-window: per-block LDS histogram -> 8 cursor atomics ->
// dense per-(block,window) runs in q. Reads edges once; writes ~256B runs.
// ---------------------------------------------------------------------------
__global__ __launch_bounds__(256) void bin_kernel(const int2* __restrict__ edges, int E,
                                                  int* __restrict__ qcur,
                                                  int2* __restrict__ q) {
  __shared__ int cnt[NWIN], base[NWIN], rank[NWIN];
  int e = blockIdx.x * 256 + threadIdx.x;
  if (threadIdx.x < NWIN) { cnt[threadIdx.x] = 0; rank[threadIdx.x] = 0; }
  __syncthreads();
  int2 sd;
  int w = 0;
  bool valid = e < E;
  if (valid) {
    sd = edges[e];
    w = sd.y / WIN;
    atomicAdd(&cnt[w], 1);
  }
  __syncthreads();
  if (threadIdx.x < NWIN && cnt[threadIdx.x] > 0)
    base[threadIdx.x] = atomicAdd(&qcur[threadIdx.x], cnt[threadIdx.x]);
  __syncthreads();
  if (valid) {
    int off = atomicAdd(&rank[w], 1);
    q[base[w] + off] = sd;
  }
}

// ---------------------------------------------------------------------------
// XCD-aware work-stealing CSR fill. Each block prefers chunks of the window
// matching its PHYSICAL XCD (s_getreg HW_REG_XCC_ID, hwreg 20 - measured
// learn_hip m09); steals from other windows once its own is drained. Correct
// for any block->XCD mapping (stealing covers every chunk exactly once).
// Writes into window p's ~800KB col region come (almost) only from XCD p ->
// dense L2 line fill, single writeback. row_ptr doubles as per-dst cursor.
// ---------------------------------------------------------------------------
__global__ __launch_bounds__(256) void fill_kernel(const int2* __restrict__ q,
                                                   const int* __restrict__ qbase,
                                                   int* __restrict__ claim,
                                                   int* __restrict__ row_ptr,
                                                   int* __restrict__ col) {
  __shared__ int s_p, s_c;
  // GETREG_IMMED(size=4, offset=0, id=20/HW_REG_XCC_ID) = 20 | (3<<11) = 6164
  int xcd = __builtin_amdgcn_s_getreg(6164) & (NWIN - 1);
  while (true) {
    if (threadIdx.x == 0) {
      int found = -1, chunk = 0;
      for (int i = 0; i < NWIN; i++) {
        int p = (xcd + i) & (NWIN - 1);
        int nch = (qbase[p + 1] - qbase[p] + 255) >> 8;
        int c = atomicAdd(&claim[p], 1);
        if (c < nch) { found = p; chunk = c; break; }
      }
      s_p = found;
      s_c = chunk;
    }
    __syncthreads();
    int p = s_p, c = s_c;
    __syncthreads();
    if (p < 0) break;
    int idx = qbase[p] + c * 256 + threadIdx.x;
    if (idx < qbase[p + 1]) {
      int2 sd = q[idx];
      int pos = atomicAdd(&row_ptr[sd.y], 1);
      col[pos] = sd.x;
    }
  }
}

// ---------------------------------------------------------------------------
// Gather mean-agg, 128-dim bf16 rows: 16 lanes/node, bf16x8 (16B) per lane.
// ---------------------------------------------------------------------------
__global__ __launch_bounds__(256) void gather128_kernel(const ushort_t* __restrict__ feat,
                                                        const int* __restrict__ col,
                                                        const int* __restrict__ row_end,
                                                        const int* __restrict__ degi,
                                                        ushort_t* __restrict__ outp) {
  int tid = blockIdx.x * 256 + threadIdx.x;
  int n = tid >> 4;
  if (n >= NN) return;
  int g = tid & 15;
  int d = degi[n];
  int start = row_end[n] - d;
  float acc[8];
#pragma unroll
  for (int j = 0; j < 8; j++) acc[j] = 0.f;
#pragma unroll 4
  for (int i = 0; i < d; i++) {
    int src = col[start + i];
    bf16x8 v = *(const bf16x8*)(feat + (size_t)src * DH + g * 8);
#pragma unroll
    for (int j = 0; j < 8; j++) acc[j] += bf2f(v[j]);
  }
  float inv = 1.0f / (float)max(d, 1);
  bf16x8 o;
#pragma unroll
  for (int j = 0; j < 8; j++) o[j] = f2bf(acc[j] * inv);
  *(bf16x8*)(outp + (size_t)n * DH + g * 8) = o;
}

// ---------------------------------------------------------------------------
// Gather mean-agg, 64-dim bf16 rows: 8 lanes/node, bf16x8 per lane.
// ---------------------------------------------------------------------------
__global__ __launch_bounds__(256) void gather64_kernel(const ushort_t* __restrict__ feat,
                                                       const int* __restrict__ col,
                                                       const int* __restrict__ row_end,
                                                       const int* __restrict__ degi,
                                                       ushort_t* __restrict__ outp) {
  int tid = blockIdx.x * 256 + threadIdx.x;
  int n = tid >> 3;
  if (n >= NN) return;
  int g = tid & 7;
  int d = degi[n];
  int start = row_end[n] - d;
  float acc[8];
#pragma unroll
  for (int j = 0; j < 8; j++) acc[j] = 0.f;
#pragma unroll 4
  for (int i = 0; i < d; i++) {
    int src = col[start + i];
    bf16x8 v = *(const bf16x8*)(feat + (size_t)src * DOUT + g * 8);
#pragma unroll
    for (int j = 0; j < 8; j++) acc[j] += bf2f(v[j]);
  }
  float inv = 1.0f / (float)max(d, 1);
  bf16x8 o;
#pragma unroll
  for (int j = 0; j < 8; j++) o[j] = f2bf(acc[j] * inv);
  *(bf16x8*)(outp + (size_t)n * DOUT + g * 8) = o;
}

// ---------------------------------------------------------------------------
// Weight conversion: Wb1[128][256]=[W1l|W1r], Wb2l[64][128], Wb2r[64][128].
// ---------------------------------------------------------------------------
__global__ __launch_bounds__(256) void convw_kernel(const float* __restrict__ W1l,
                                                    const float* __restrict__ W1r,
                                                    const float* __restrict__ W2l,
                                                    const float* __restrict__ W2r,
                                                    ushort_t* __restrict__ Wb1,
                                                    ushort_t* __restrict__ Wb2l,
                                                    ushort_t* __restrict__ Wb2r) {
  int tid = blockIdx.x * 256 + threadIdx.x;
  if (tid < 128 * 256) {
    int n = tid >> 8, k = tid & 255;
    float v = (k < 128) ? W1l[n * 128 + k] : W1r[n * 128 + (k - 128)];
    Wb1[tid] = (ushort_t)f2bf(v);
  } else if (tid < 128 * 256 + 64 * 128) {
    int t2 = tid - 128 * 256;
    Wb2l[t2] = (ushort_t)f2bf(W2l[t2]);
  } else if (tid < 128 * 256 + 2 * 64 * 128) {
    int t2 = tid - 128 * 256 - 64 * 128;
    Wb2r[t2] = (ushort_t)f2bf(W2r[t2]);
  }
}

// ---------------------------------------------------------------------------
// Layer 1 MFMA GEMM, 4x M-blocked: wave = 64 rows x 128 cols, block = 2 waves.
// Epilogue: h bf16 + fused BN column sums (LDS + atomics).
// ---------------------------------------------------------------------------
__global__ __launch_bounds__(128, 2) void gemm1_mfma(const ushort_t* __restrict__ s,
                                                     const ushort_t* __restrict__ x,
                                                     const ushort_t* __restrict__ Wb,
                                                     const float* __restrict__ b1l,
                                                     ushort_t* __restrict__ h,
                                                     float* __restrict__ sums,
                                                     float* __restrict__ sumsq) {
  __shared__ float sred[2][2][DH];
  int w = threadIdx.x >> 6;
  int l = threadIdx.x & 63;
  int m = l & 15;
  int q = l >> 4;
  int rowblk = blockIdx.x * 128 + w * 64;
  int rl[4];
#pragma unroll
  for (int mt = 0; mt < 4; mt++) {
    int row = rowblk + mt * 16 + m;
    rl[mt] = row < NN ? row : NN - 1;
  }
  f32x4 acc[4][8];
#pragma unroll
  for (int mt = 0; mt < 4; mt++)
#pragma unroll
    for (int t = 0; t < 8; t++) acc[mt][t] = (f32x4){0.f, 0.f, 0.f, 0.f};
#pragma unroll
  for (int ks = 0; ks < 8; ks++) {
    const ushort_t* base = (ks < 4) ? s : x;
    int off = (ks & 3) * 32 + q * 8;
    bf16x8 a[4];
#pragma unroll
    for (int mt = 0; mt < 4; mt++)
      a[mt] = *(const bf16x8*)(base + (size_t)rl[mt] * DH + off);
#pragma unroll
    for (int t = 0; t < 8; t++) {
      bf16x8 bf = *(const bf16x8*)(Wb + (size_t)(t * 16 + m) * 256 + ks * 32 + q * 8);
#pragma unroll
      for (int mt = 0; mt < 4; mt++)
        acc[mt][t] = __builtin_amdgcn_mfma_f32_16x16x32_bf16(a[mt], bf, acc[mt][t], 0, 0, 0);
    }
  }
  float psum[8], psq[8];
#pragma unroll
  for (int t = 0; t < 8; t++) { psum[t] = 0.f; psq[t] = 0.f; }
#pragma unroll
  for (int t = 0; t < 8; t++) {
    float bias = b1l[t * 16 + m];
#pragma unroll
    for (int mt = 0; mt < 4; mt++) {
#pragma unroll
      for (int r = 0; r < 4; r++) {
        int rr = rowblk + mt * 16 + q * 4 + r;
        if (rr < NN) {
          float vv = acc[mt][t][r] + bias;
          h[(size_t)rr * DH + t * 16 + m] = (ushort_t)f2bf(vv);
          psum[t] += vv;
          psq[t] += vv * vv;
        }
      }
    }
  }
#pragma unroll
  for (int t = 0; t < 8; t++) {
    psum[t] += __shfl_xor(psum[t], 16, 64);
    psum[t] += __shfl_xor(psum[t], 32, 64);
    psq[t] += __shfl_xor(psq[t], 16, 64);
    psq[t] += __shfl_xor(psq[t], 32, 64);
  }
  if (q == 0) {
#pragma unroll
    for (int t = 0; t < 8; t++) {
      sred[0][w][t * 16 + m] = psum[t];
      sred[1][w][t * 16 + m] = psq[t];
    }
  }
  __syncthreads();
  int tid = threadIdx.x;
  atomicAdd(&sums[tid], sred[0][0][tid] + sred[0][1][tid]);
  atomicAdd(&sumsq[tid], sred[1][0][tid] + sred[1][1][tid]);
}

// stats -> per-column scale/shift (tiny).
__global__ __launch_bounds__(128) void bn_prep_kernel(const float* __restrict__ sums,
                                                      const float* __restrict__ sumsq,
                                                      const float* __restrict__ gamma,
                                                      const float* __restrict__ beta,
                                                      float* __restrict__ scl,
                                                      float* __restrict__ sh) {
  int c = threadIdx.x;
  float mean = sums[c] * (1.0f / NN);
  float var = sumsq[c] * (1.0f / NN) - mean * mean;
  float s = gamma[c] * rsqrtf(var + 1e-5f);
  scl[c] = s;
  sh[c] = beta[c] - mean * s;
}

// BN+ReLU A-fragment from bf16 h with preloaded scl/sh vectors.
__device__ __forceinline__ bf16x8 bn_frag2(bf16x8 hv, float4 s0, float4 s1,
                                           float4 h0, float4 h1) {
  bf16x8 af;
  af[0] = f2bf(fmaxf(bf2f(hv[0]) * s0.x + h0.x, 0.f));
  af[1] = f2bf(fmaxf(bf2f(hv[1]) * s0.y + h0.y, 0.f));
  af[2] = f2bf(fmaxf(bf2f(hv[2]) * s0.z + h0.z, 0.f));
  af[3] = f2bf(fmaxf(bf2f(hv[3]) * s0.w + h0.w, 0.f));
  af[4] = f2bf(fmaxf(bf2f(hv[4]) * s1.x + h1.x, 0.f));
  af[5] = f2bf(fmaxf(bf2f(hv[5]) * s1.y + h1.y, 0.f));
  af[6] = f2bf(fmaxf(bf2f(hv[6]) * s1.z + h1.z, 0.f));
  af[7] = f2bf(fmaxf(bf2f(hv[7]) * s1.w + h1.w, 0.f));
  return af;
}

// ---------------------------------------------------------------------------
// z = relu(bn(h)) @ W2l^T  [N x 64] bf16, K=128. 4x M-blocked.
// ---------------------------------------------------------------------------
__global__ __launch_bounds__(128, 2) void z_mfma(const ushort_t* __restrict__ hin,
                                                 const float* __restrict__ scl,
                                                 const float* __restrict__ sh,
                                                 const ushort_t* __restrict__ Wb2l,
                                                 ushort_t* __restrict__ z) {
  int w = threadIdx.x >> 6;
  int l = threadIdx.x & 63;
  int m = l & 15;
  int q = l >> 4;
  int rowblk = blockIdx.x * 128 + w * 64;
  int rl[4];
#pragma unroll
  for (int mt = 0; mt < 4; mt++) {
    int row = rowblk + mt * 16 + m;
    rl[mt] = row < NN ? row : NN - 1;
  }
  f32x4 acc[4][4];
#pragma unroll
  for (int mt = 0; mt < 4; mt++)
#pragma unroll
    for (int t = 0; t < 4; t++) acc[mt][t] = (f32x4){0.f, 0.f, 0.f, 0.f};
#pragma unroll
  for (int ks = 0; ks < 4; ks++) {
    int k0 = ks * 32 + q * 8;
    float4 s0 = ((const float4*)(scl + k0))[0];
    float4 s1 = ((const float4*)(scl + k0))[1];
    float4 h0 = ((const float4*)(sh + k0))[0];
    float4 h1 = ((const float4*)(sh + k0))[1];
    bf16x8 bfr[4];
#pragma unroll
    for (int t = 0; t < 4; t++)
      bfr[t] = *(const bf16x8*)(Wb2l + (size_t)(t * 16 + m) * DH + k0);
#pragma unroll
    for (int mt = 0; mt < 4; mt++) {
      bf16x8 hv = *(const bf16x8*)(hin + (size_t)rl[mt] * DH + k0);
      bf16x8 af = bn_frag2(hv, s0, s1, h0, h1);
#pragma unroll
      for (int t = 0; t < 4; t++)
        acc[mt][t] = __builtin_amdgcn_mfma_f32_16x16x32_bf16(af, bfr[t], acc[mt][t], 0, 0, 0);
    }
  }
#pragma unroll
  for (int mt = 0; mt < 4; mt++)
#pragma unroll
    for (int t = 0; t < 4; t++)
#pragma unroll
      for (int r = 0; r < 4; r++) {
        int rr = rowblk + mt * 16 + q * 4 + r;
        if (rr < NN) z[(size_t)rr * DOUT + t * 16 + m] = (ushort_t)f2bf(acc[mt][t][r]);
      }
}

// ---------------------------------------------------------------------------
// Layer 2: out = zagg + relu(bn(h)) @ W2r^T + b2, log_softmax. 4x M-blocked.
// ---------------------------------------------------------------------------
__global__ __launch_bounds__(128, 2) void gemm2_mfma(const ushort_t* __restrict__ hin,
                                                     const float* __restrict__ scl,
                                                     const float* __restrict__ sh,
                                                     const ushort_t* __restrict__ zagg,
                                                     const ushort_t* __restrict__ Wb2r,
                                                     const float* __restrict__ b2l,
                                                     float* __restrict__ out) {
  int w = threadIdx.x >> 6;
  int l = threadIdx.x & 63;
  int m = l & 15;
  int q = l >> 4;
  int rowblk = blockIdx.x * 128 + w * 64;
  int rl[4];
#pragma unroll
  for (int mt = 0; mt < 4; mt++) {
    int row = rowblk + mt * 16 + m;
    rl[mt] = row < NN ? row : NN - 1;
  }
  f32x4 acc[4][4];
#pragma unroll
  for (int mt = 0; mt < 4; mt++)
#pragma unroll
    for (int t = 0; t < 4; t++) acc[mt][t] = (f32x4){0.f, 0.f, 0.f, 0.f};
#pragma unroll
  for (int ks = 0; ks < 4; ks++) {
    int k0 = ks * 32 + q * 8;
    float4 s0 = ((const float4*)(scl + k0))[0];
    float4 s1 = ((const float4*)(scl + k0))[1];
    float4 h0 = ((const float4*)(sh + k0))[0];
    float4 h1 = ((const float4*)(sh + k0))[1];
    bf16x8 bfr[4];
#pragma unroll
    for (int t = 0; t < 4; t++)
      bfr[t] = *(const bf16x8*)(Wb2r + (size_t)(t * 16 + m) * DH + k0);
#pragma unroll
    for (int mt = 0; mt < 4; mt++) {
      bf16x8 hv = *(const bf16x8*)(hin + (size_t)rl[mt] * DH + k0);
      bf16x8 af = bn_frag2(hv, s0, s1, h0, h1);
#pragma unroll
      for (int t = 0; t < 4; t++)
        acc[mt][t] = __builtin_amdgcn_mfma_f32_16x16x32_bf16(af, bfr[t], acc[mt][t], 0, 0, 0);
    }
  }
#pragma unroll
  for (int mt = 0; mt < 4; mt++) {
    float v[4][4];
#pragma unroll
    for (int t = 0; t < 4; t++) {
      float bias = b2l[t * 16 + m];
#pragma unroll
      for (int r = 0; r < 4; r++) {
        int rr = rowblk + mt * 16 + q * 4 + r;
        float zg = (rr < NN) ? bf2f((short)zagg[(size_t)rr * DOUT + t * 16 + m]) : 0.f;
        v[t][r] = acc[mt][t][r] + zg + bias;
      }
    }
#pragma unroll
    for (int r = 0; r < 4; r++) {
      float mx = fmaxf(fmaxf(v[0][r], v[1][r]), fmaxf(v[2][r], v[3][r]));
      mx = fmaxf(mx, __shfl_xor(mx, 1, 64));
      mx = fmaxf(mx, __shfl_xor(mx, 2, 64));
      mx = fmaxf(mx, __shfl_xor(mx, 4, 64));
      mx = fmaxf(mx, __shfl_xor(mx, 8, 64));
      float se = __expf(v[0][r] - mx) + __expf(v[1][r] - mx) +
                 __expf(v[2][r] - mx) + __expf(v[3][r] - mx);
      se += __shfl_xor(se, 1, 64);
      se += __shfl_xor(se, 2, 64);
      se += __shfl_xor(se, 4, 64);
      se += __shfl_xor(se, 8, 64);
      float lse = mx + logf(se);
      int rr = rowblk + mt * 16 + q * 4 + r;
      if (rr < NN) {
#pragma unroll
        for (int t = 0; t < 4; t++)
          out[(size_t)rr * DOUT + t * 16 + m] = v[t][r] - lse;
      }
    }
  }
}

// ---------------------------------------------------------------------------
extern "C" void kernel_launch(void* const* d_in, const int* in_sizes, int n_in,
                              void* d_out, int out_size, void* d_ws, size_t ws_size,
                              hipStream_t stream) {
  const float* x = (const float*)d_in[0];
  const int* ei = (const int*)d_in[1];
  const float* W1l = (const float*)d_in[2];
  const float* b1l = (const float*)d_in[3];
  const float* W1r = (const float*)d_in[4];
  const float* gamma = (const float*)d_in[5];
  const float* beta = (const float*)d_in[6];
  const float* W2l = (const float*)d_in[7];
  const float* b2l = (const float*)d_in[8];
  const float* W2r = (const float*)d_in[9];
  float* out = (float*)d_out;
  int E = in_sizes[1] / 2;
  int nblkg = (NN + 127) / 128;

  // workspace (~110 MB):
  //   u0 (25.6 MB): edges int2[E] (first half) + q int2[E] (second half);
  //     later reused as z_bf16[N*64] (overlaps edges) + zagg_bf16[N*64]
  //     (overlaps q). Ordering: edges dead after bin; q dead after fill;
  //     z written after gemm1 (edges dead); zagg written by gather64 (q dead).
  //   x_bf16 | s_bf16 | h_bf16 | degi | row_ptr | col | stats | qmeta | W tables
  char* p = (char*)d_ws;
  int2* edges = (int2*)p;
  ushort_t* z_bf = (ushort_t*)p;
  int2* q = (int2*)(p + (size_t)NN * DOUT * sizeof(ushort_t));  // 12.8 MB in
  ushort_t* zagg_bf = z_bf + (size_t)NN * DOUT;
  p += (size_t)NN * DOUT * 2 * sizeof(ushort_t);
  ushort_t* x_bf = (ushort_t*)p;  p += (size_t)NN * DH * sizeof(ushort_t);
  ushort_t* s_bf = (ushort_t*)p;  p += (size_t)NN * DH * sizeof(ushort_t);
  ushort_t* h_bf = (ushort_t*)p;  p += (size_t)NN * DH * sizeof(ushort_t);
  int* degi = (int*)p;            p += NN * sizeof(int);
  int* row_ptr = (int*)p;         p += NN * sizeof(int);
  int* col = (int*)p;             p += (size_t)E * sizeof(int);
  float* sums = (float*)p;        p += DH * sizeof(float);
  float* sumsq = (float*)p;       p += DH * sizeof(float);
  float* scl = (float*)p;         p += DH * sizeof(float);
  float* sh = (float*)p;          p += DH * sizeof(float);
  int* flag = (int*)p;            p += 4 * sizeof(int);
  int* qbase = (int*)p;           p += 12 * sizeof(int);  // [9] padded
  int* qcur = (int*)p;            p += NWIN * sizeof(int);
  int* claim = (int*)p;           p += NWIN * sizeof(int);
  ushort_t* Wb1 = (ushort_t*)p;   p += 128 * 256 * sizeof(ushort_t);
  ushort_t* Wb2l = (ushort_t*)p;  p += 64 * 128 * sizeof(ushort_t);
  ushort_t* Wb2r = (ushort_t*)p;

  hipMemsetAsync(degi, 0, NN * sizeof(int), stream);
  hipMemsetAsync(sums, 0, 2 * DH * sizeof(float), stream);

  detect_kernel<<<1, 256, 0, stream>>>(ei, E, flag);
  convw_kernel<<<192, 256, 0, stream>>>(W1l, W1r, W2l, W2r, Wb1, Wb2l, Wb2r);
  convx_kernel<<<(NN * DH / 8 + 255) / 256, 256, 0, stream>>>(x, x_bf);
  convert_deg_kernel<<<(E + 255) / 256, 256, 0, stream>>>(ei, E, flag, edges, degi);
  scan_kernel<<<1, 1024, 0, stream>>>(degi, row_ptr);
  qinit_kernel<<<1, 64, 0, stream>>>(row_ptr, E, qbase, qcur, claim);
  bin_kernel<<<(E + 255) / 256, 256, 0, stream>>>(edges, E, qcur, q);
  fill_kernel<<<2048, 256, 0, stream>>>(q, qbase, claim, row_ptr, col);
  gather128_kernel<<<(NN * 16 + 255) / 256, 256, 0, stream>>>(x_bf, col, row_ptr, degi, s_bf);
  gemm1_mfma<<<nblkg, 128, 0, stream>>>(s_bf, x_bf, Wb1, b1l, h_bf, sums, sumsq);
  bn_prep_kernel<<<1, 128, 0, stream>>>(sums, sumsq, gamma, beta, scl, sh);
  z_mfma<<<nblkg, 128, 0, stream>>>(h_bf, scl, sh, Wb2l, z_bf);
  gather64_kernel<<<(NN * 8 + 255) / 256, 256, 0, stream>>>(z_bf, col, row_ptr, degi, zagg_bf);
  gemm2_mfma<<<nblkg, 128, 0, stream>>>(h_bf, scl, sh, zagg_bf, Wb2r, b2l, out);
}

// Round 10
// 463.722 us; speedup vs baseline: 1.6758x; 1.6758x over previous
//
#include <hip/hip_runtime.h>
#include <math.h>

#define NN 100000
#define DH 128
#define DOUT 64
#define NWIN 128
#define WIN 782        // ceil(NN / NWIN); 127*782 = 99314 < NN
#define BIN_EPB 8192   // edges per bin block

typedef __attribute__((ext_vector_type(8))) short bf16x8;
typedef __attribute__((ext_vector_type(4))) float f32x4;
typedef unsigned short ushort_t;

__device__ __forceinline__ short f2bf(float f) {
  unsigned u = __float_as_uint(f);
  unsigned r = (u + 0x7fffu + ((u >> 16) & 1u)) >> 16;
  return (short)r;
}
__device__ __forceinline__ float bf2f(short b) {
  return __uint_as_float(((unsigned)(unsigned short)b) << 16);
}

// ---------------------------------------------------------------------------
// Edge-index dtype detector (int64 reference vs int32 harness doc).
// ---------------------------------------------------------------------------
__global__ __launch_bounds__(256) void detect_kernel(const int* __restrict__ ei, int E,
                                                     int* __restrict__ flag) {
  const long long* e64 = (const long long*)ei;
  int lim = E < 1024 ? E : 1024;
  int ok = 1;
  for (int i = threadIdx.x; i < lim; i += 256) {
    long long v = e64[i];
    if (v < 0 || v >= NN) ok = 0;
  }
  __shared__ int s_ok;
  if (threadIdx.x == 0) s_ok = 1;
  __syncthreads();
  if (!ok) atomicAnd(&s_ok, 0);
  __syncthreads();
  if (threadIdx.x == 0) *flag = s_ok;
}

__device__ __forceinline__ int edge_at(const int* __restrict__ ei, int is64, size_t pos) {
  return is64 ? (int)(((const long long*)ei)[pos]) : ei[pos];
}

// ---------------------------------------------------------------------------
// x (fp32) -> x_bf16, 8 elems/thread.
// ---------------------------------------------------------------------------
__global__ __launch_bounds__(256) void convx_kernel(const float* __restrict__ x,
                                                    ushort_t* __restrict__ xb) {
  size_t i = ((size_t)blockIdx.x * 256 + threadIdx.x) * 8;
  if (i >= (size_t)NN * DH) return;
  float4 f0 = ((const float4*)(x + i))[0];
  float4 f1 = ((const float4*)(x + i))[1];
  bf16x8 o;
  o[0] = f2bf(f0.x); o[1] = f2bf(f0.y); o[2] = f2bf(f0.z); o[3] = f2bf(f0.w);
  o[4] = f2bf(f1.x); o[5] = f2bf(f1.y); o[6] = f2bf(f1.z); o[7] = f2bf(f1.w);
  *(bf16x8*)(xb + i) = o;
}

// ---------------------------------------------------------------------------
// One pass over edges: pack to int2 {src,dst} AND build degree histogram.
// ---------------------------------------------------------------------------
__global__ __launch_bounds__(256) void convert_deg_kernel(const int* __restrict__ ei, int E,
                                                          const int* __restrict__ flag,
                                                          int2* __restrict__ edges,
                                                          int* __restrict__ degi) {
  int e = blockIdx.x * 256 + threadIdx.x;
  if (e >= E) return;
  int is64 = *flag;
  int src = edge_at(ei, is64, (size_t)e);
  int dst = edge_at(ei, is64, (size_t)E + e);
  edges[e] = make_int2(src, dst);
  atomicAdd(&degi[dst], 1);
}

// ---------------------------------------------------------------------------
// Exclusive scan of degi -> row_ptr. Single block, 1024 thr x 4 elems/thr.
// ---------------------------------------------------------------------------
__global__ __launch_bounds__(1024) void scan_kernel(const int* __restrict__ degi,
                                                    int* __restrict__ row_ptr) {
  __shared__ int warp_sums[16];
  __shared__ int s_offset;
  int lane = threadIdx.x & 63;
  int wid = threadIdx.x >> 6;
  if (threadIdx.x == 0) s_offset = 0;
  __syncthreads();
  for (int base = 0; base < NN; base += 4096) {
    int i0 = base + threadIdx.x * 4;
    int v0 = (i0 + 0 < NN) ? degi[i0 + 0] : 0;
    int v1 = (i0 + 1 < NN) ? degi[i0 + 1] : 0;
    int v2 = (i0 + 2 < NN) ? degi[i0 + 2] : 0;
    int v3 = (i0 + 3 < NN) ? degi[i0 + 3] : 0;
    int tot = v0 + v1 + v2 + v3;
    int sv = tot;
#pragma unroll
    for (int o = 1; o < 64; o <<= 1) {
      int t = __shfl_up(sv, o, 64);
      if (lane >= o) sv += t;
    }
    if (lane == 63) warp_sums[wid] = sv;
    __syncthreads();
    if (wid == 0 && lane < 16) {
      int ws = warp_sums[lane];
#pragma unroll
      for (int o = 1; o < 16; o <<= 1) {
        int t = __shfl_up(ws, o, 16);
        if (lane >= o) ws += t;
      }
      warp_sums[lane] = ws;
    }
    __syncthreads();
    int wave_off = (wid == 0) ? 0 : warp_sums[wid - 1];
    int excl = s_offset + wave_off + sv - tot;
    if (i0 + 0 < NN) row_ptr[i0 + 0] = excl;
    if (i0 + 1 < NN) row_ptr[i0 + 1] = excl + v0;
    if (i0 + 2 < NN) row_ptr[i0 + 2] = excl + v0 + v1;
    if (i0 + 3 < NN) row_ptr[i0 + 3] = excl + v0 + v1 + v2;
    __syncthreads();
    if (threadIdx.x == 1023) s_offset = excl + tot;
    __syncthreads();
  }
}

// ---------------------------------------------------------------------------
// qbase[p] = first col index of dst-window p (from row_ptr); qcur = bin
// write cursors. Separate dispatch to avoid coherence games.
// ---------------------------------------------------------------------------
__global__ __launch_bounds__(256) void qinit_kernel(const int* __restrict__ row_ptr, int E,
                                                    int* __restrict__ qbase,
                                                    int* __restrict__ qcur) {
  int t = threadIdx.x;
  if (t < NWIN) {
    int b = row_ptr[t * WIN];
    qbase[t] = b;
    qcur[t] = b;
  }
  if (t == NWIN) qbase[NWIN] = E;
}

// ---------------------------------------------------------------------------
// Bin edges by dst-window (128 windows): per-block LDS histogram over
// BIN_EPB edges -> <=128 global cursor atomics -> dense ~64-edge runs in q.
// ---------------------------------------------------------------------------
__global__ __launch_bounds__(256) void bin_kernel(const int2* __restrict__ edges, int E,
                                                  int* __restrict__ qcur,
                                                  int2* __restrict__ q) {
  __shared__ int cnt[NWIN], base[NWIN], rank[NWIN];
  int e0 = blockIdx.x * BIN_EPB;
  for (int t = threadIdx.x; t < NWIN; t += 256) { cnt[t] = 0; rank[t] = 0; }
  __syncthreads();
  for (int i = threadIdx.x; i < BIN_EPB; i += 256) {
    int e = e0 + i;
    if (e < E) {
      int dst = edges[e].y;
      atomicAdd(&cnt[dst / WIN], 1);
    }
  }
  __syncthreads();
  for (int t = threadIdx.x; t < NWIN; t += 256)
    if (cnt[t] > 0) base[t] = atomicAdd(&qcur[t], cnt[t]);
  __syncthreads();
  for (int i = threadIdx.x; i < BIN_EPB; i += 256) {
    int e = e0 + i;
    if (e < E) {
      int2 sd = edges[e];
      int w = sd.y / WIN;
      int off = atomicAdd(&rank[w], 1);
      q[base[w] + off] = sd;
    }
  }
}

// ---------------------------------------------------------------------------
// CSR fill, one block per dst-window: per-dst cursors live in LDS (cheap
// atomics), col writes confined to this window's ~50KB region -> written by
// ONE CU / ONE XCD -> dense L2 line fill, single writeback. row_ptr is NOT
// modified (gathers read it as row start).
// ---------------------------------------------------------------------------
__global__ __launch_bounds__(512) void fill_kernel(const int2* __restrict__ q,
                                                   const int* __restrict__ qbase,
                                                   const int* __restrict__ row_ptr,
                                                   int* __restrict__ col) {
  __shared__ int cur[WIN];
  int p = blockIdx.x;
  int n0 = p * WIN;
  int nw = min(WIN, NN - n0);
  for (int n = threadIdx.x; n < nw; n += 512) cur[n] = row_ptr[n0 + n];
  __syncthreads();
  int qs = qbase[p], qe = qbase[p + 1];
  for (int i = qs + threadIdx.x; i < qe; i += 512) {
    int2 sd = q[i];
    int pos = atomicAdd(&cur[sd.y - n0], 1);
    col[pos] = sd.x;
  }
}

// ---------------------------------------------------------------------------
// Gather mean-agg, 128-dim bf16 rows: 16 lanes/node, bf16x8 (16B) per lane.
// ---------------------------------------------------------------------------
__global__ __launch_bounds__(256) void gather128_kernel(const ushort_t* __restrict__ feat,
                                                        const int* __restrict__ col,
                                                        const int* __restrict__ row_ptr,
                                                        const int* __restrict__ degi,
                                                        ushort_t* __restrict__ outp) {
  int tid = blockIdx.x * 256 + threadIdx.x;
  int n = tid >> 4;
  if (n >= NN) return;
  int g = tid & 15;
  int d = degi[n];
  int start = row_ptr[n];
  float acc[8];
#pragma unroll
  for (int j = 0; j < 8; j++) acc[j] = 0.f;
#pragma unroll 4
  for (int i = 0; i < d; i++) {
    int src = col[start + i];
    bf16x8 v = *(const bf16x8*)(feat + (size_t)src * DH + g * 8);
#pragma unroll
    for (int j = 0; j < 8; j++) acc[j] += bf2f(v[j]);
  }
  float inv = 1.0f / (float)max(d, 1);
  bf16x8 o;
#pragma unroll
  for (int j = 0; j < 8; j++) o[j] = f2bf(acc[j] * inv);
  *(bf16x8*)(outp + (size_t)n * DH + g * 8) = o;
}

// ---------------------------------------------------------------------------
// Gather mean-agg, 64-dim bf16 rows: 8 lanes/node, bf16x8 per lane.
// ---------------------------------------------------------------------------
__global__ __launch_bounds__(256) void gather64_kernel(const ushort_t* __restrict__ feat,
                                                       const int* __restrict__ col,
                                                       const int* __restrict__ row_ptr,
                                                       const int* __restrict__ degi,
                                                       ushort_t* __restrict__ outp) {
  int tid = blockIdx.x * 256 + threadIdx.x;
  int n = tid >> 3;
  if (n >= NN) return;
  int g = tid & 7;
  int d = degi[n];
  int start = row_ptr[n];
  float acc[8];
#pragma unroll
  for (int j = 0; j < 8; j++) acc[j] = 0.f;
#pragma unroll 4
  for (int i = 0; i < d; i++) {
    int src = col[start + i];
    bf16x8 v = *(const bf16x8*)(feat + (size_t)src * DOUT + g * 8);
#pragma unroll
    for (int j = 0; j < 8; j++) acc[j] += bf2f(v[j]);
  }
  float inv = 1.0f / (float)max(d, 1);
  bf16x8 o;
#pragma unroll
  for (int j = 0; j < 8; j++) o[j] = f2bf(acc[j] * inv);
  *(bf16x8*)(outp + (size_t)n * DOUT + g * 8) = o;
}

// ---------------------------------------------------------------------------
// Weight conversion: Wb1[128][256]=[W1l|W1r], Wb2l[64][128], Wb2r[64][128].
// ---------------------------------------------------------------------------
__global__ __launch_bounds__(256) void convw_kernel(const float* __restrict__ W1l,
                                                    const float* __restrict__ W1r,
                                                    const float* __restrict__ W2l,
                                                    const float* __restrict__ W2r,
                                                    ushort_t* __restrict__ Wb1,
                                                    ushort_t* __restrict__ Wb2l,
                                                    ushort_t* __restrict__ Wb2r) {
  int tid = blockIdx.x * 256 + threadIdx.x;
  if (tid < 128 * 256) {
    int n = tid >> 8, k = tid & 255;
    float v = (k < 128) ? W1l[n * 128 + k] : W1r[n * 128 + (k - 128)];
    Wb1[tid] = (ushort_t)f2bf(v);
  } else if (tid < 128 * 256 + 64 * 128) {
    int t2 = tid - 128 * 256;
    Wb2l[t2] = (ushort_t)f2bf(W2l[t2]);
  } else if (tid < 128 * 256 + 2 * 64 * 128) {
    int t2 = tid - 128 * 256 - 64 * 128;
    Wb2r[t2] = (ushort_t)f2bf(W2r[t2]);
  }
}

// ---------------------------------------------------------------------------
// Layer 1 MFMA GEMM, 4x M-blocked: wave = 64 rows x 128 cols, block = 2 waves.
// Epilogue: h bf16 + fused BN column sums (LDS + atomics).
// ---------------------------------------------------------------------------
__global__ __launch_bounds__(128, 2) void gemm1_mfma(const ushort_t* __restrict__ s,
                                                     const ushort_t* __restrict__ x,
                                                     const ushort_t* __restrict__ Wb,
                                                     const float* __restrict__ b1l,
                                                     ushort_t* __restrict__ h,
                                                     float* __restrict__ sums,
                                                     float* __restrict__ sumsq) {
  __shared__ float sred[2][2][DH];
  int w = threadIdx.x >> 6;
  int l = threadIdx.x & 63;
  int m = l & 15;
  int q = l >> 4;
  int rowblk = blockIdx.x * 128 + w * 64;
  int rl[4];
#pragma unroll
  for (int mt = 0; mt < 4; mt++) {
    int row = rowblk + mt * 16 + m;
    rl[mt] = row < NN ? row : NN - 1;
  }
  f32x4 acc[4][8];
#pragma unroll
  for (int mt = 0; mt < 4; mt++)
#pragma unroll
    for (int t = 0; t < 8; t++) acc[mt][t] = (f32x4){0.f, 0.f, 0.f, 0.f};
#pragma unroll
  for (int ks = 0; ks < 8; ks++) {
    const ushort_t* base = (ks < 4) ? s : x;
    int off = (ks & 3) * 32 + q * 8;
    bf16x8 a[4];
#pragma unroll
    for (int mt = 0; mt < 4; mt++)
      a[mt] = *(const bf16x8*)(base + (size_t)rl[mt] * DH + off);
#pragma unroll
    for (int t = 0; t < 8; t++) {
      bf16x8 bf = *(const bf16x8*)(Wb + (size_t)(t * 16 + m) * 256 + ks * 32 + q * 8);
#pragma unroll
      for (int mt = 0; mt < 4; mt++)
        acc[mt][t] = __builtin_amdgcn_mfma_f32_16x16x32_bf16(a[mt], bf, acc[mt][t], 0, 0, 0);
    }
  }
  float psum[8], psq[8];
#pragma unroll
  for (int t = 0; t < 8; t++) { psum[t] = 0.f; psq[t] = 0.f; }
#pragma unroll
  for (int t = 0; t < 8; t++) {
    float bias = b1l[t * 16 + m];
#pragma unroll
    for (int mt = 0; mt < 4; mt++) {
#pragma unroll
      for (int r = 0; r < 4; r++) {
        int rr = rowblk + mt * 16 + q * 4 + r;
        if (rr < NN) {
          float vv = acc[mt][t][r] + bias;
          h[(size_t)rr * DH + t * 16 + m] = (ushort_t)f2bf(vv);
          psum[t] += vv;
          psq[t] += vv * vv;
        }
      }
    }
  }
#pragma unroll
  for (int t = 0; t < 8; t++) {
    psum[t] += __shfl_xor(psum[t], 16, 64);
    psum[t] += __shfl_xor(psum[t], 32, 64);
    psq[t] += __shfl_xor(psq[t], 16, 64);
    psq[t] += __shfl_xor(psq[t], 32, 64);
  }
  if (q == 0) {
#pragma unroll
    for (int t = 0; t < 8; t++) {
      sred[0][w][t * 16 + m] = psum[t];
      sred[1][w][t * 16 + m] = psq[t];
    }
  }
  __syncthreads();
  int tid = threadIdx.x;
  atomicAdd(&sums[tid], sred[0][0][tid] + sred[0][1][tid]);
  atomicAdd(&sumsq[tid], sred[1][0][tid] + sred[1][1][tid]);
}

// stats -> per-column scale/shift (tiny).
__global__ __launch_bounds__(128) void bn_prep_kernel(const float* __restrict__ sums,
                                                      const float* __restrict__ sumsq,
                                                      const float* __restrict__ gamma,
                                                      const float* __restrict__ beta,
                                                      float* __restrict__ scl,
                                                      float* __restrict__ sh) {
  int c = threadIdx.x;
  float mean = sums[c] * (1.0f / NN);
  float var = sumsq[c] * (1.0f / NN) - mean * mean;
  float s = gamma[c] * rsqrtf(var + 1e-5f);
  scl[c] = s;
  sh[c] = beta[c] - mean * s;
}

// BN+ReLU A-fragment from bf16 h with preloaded scl/sh vectors.
__device__ __forceinline__ bf16x8 bn_frag2(bf16x8 hv, float4 s0, float4 s1,
                                           float4 h0, float4 h1) {
  bf16x8 af;
  af[0] = f2bf(fmaxf(bf2f(hv[0]) * s0.x + h0.x, 0.f));
  af[1] = f2bf(fmaxf(bf2f(hv[1]) * s0.y + h0.y, 0.f));
  af[2] = f2bf(fmaxf(bf2f(hv[2]) * s0.z + h0.z, 0.f));
  af[3] = f2bf(fmaxf(bf2f(hv[3]) * s0.w + h0.w, 0.f));
  af[4] = f2bf(fmaxf(bf2f(hv[4]) * s1.x + h1.x, 0.f));
  af[5] = f2bf(fmaxf(bf2f(hv[5]) * s1.y + h1.y, 0.f));
  af[6] = f2bf(fmaxf(bf2f(hv[6]) * s1.z + h1.z, 0.f));
  af[7] = f2bf(fmaxf(bf2f(hv[7]) * s1.w + h1.w, 0.f));
  return af;
}

// ---------------------------------------------------------------------------
// z = relu(bn(h)) @ W2l^T  [N x 64] bf16, K=128. 4x M-blocked.
// ---------------------------------------------------------------------------
__global__ __launch_bounds__(128, 2) void z_mfma(const ushort_t* __restrict__ hin,
                                                 const float* __restrict__ scl,
                                                 const float* __restrict__ sh,
                                                 const ushort_t* __restrict__ Wb2l,
                                                 ushort_t* __restrict__ z) {
  int w = threadIdx.x >> 6;
  int l = threadIdx.x & 63;
  int m = l & 15;
  int q = l >> 4;
  int rowblk = blockIdx.x * 128 + w * 64;
  int rl[4];
#pragma unroll
  for (int mt = 0; mt < 4; mt++) {
    int row = rowblk + mt * 16 + m;
    rl[mt] = row < NN ? row : NN - 1;
  }
  f32x4 acc[4][4];
#pragma unroll
  for (int mt = 0; mt < 4; mt++)
#pragma unroll
    for (int t = 0; t < 4; t++) acc[mt][t] = (f32x4){0.f, 0.f, 0.f, 0.f};
#pragma unroll
  for (int ks = 0; ks < 4; ks++) {
    int k0 = ks * 32 + q * 8;
    float4 s0 = ((const float4*)(scl + k0))[0];
    float4 s1 = ((const float4*)(scl + k0))[1];
    float4 h0 = ((const float4*)(sh + k0))[0];
    float4 h1 = ((const float4*)(sh + k0))[1];
    bf16x8 bfr[4];
#pragma unroll
    for (int t = 0; t < 4; t++)
      bfr[t] = *(const bf16x8*)(Wb2l + (size_t)(t * 16 + m) * DH + k0);
#pragma unroll
    for (int mt = 0; mt < 4; mt++) {
      bf16x8 hv = *(const bf16x8*)(hin + (size_t)rl[mt] * DH + k0);
      bf16x8 af = bn_frag2(hv, s0, s1, h0, h1);
#pragma unroll
      for (int t = 0; t < 4; t++)
        acc[mt][t] = __builtin_amdgcn_mfma_f32_16x16x32_bf16(af, bfr[t], acc[mt][t], 0, 0, 0);
    }
  }
#pragma unroll
  for (int mt = 0; mt < 4; mt++)
#pragma unroll
    for (int t = 0; t < 4; t++)
#pragma unroll
      for (int r = 0; r < 4; r++) {
        int rr = rowblk + mt * 16 + q * 4 + r;
        if (rr < NN) z[(size_t)rr * DOUT + t * 16 + m] = (ushort_t)f2bf(acc[mt][t][r]);
      }
}

// ---------------------------------------------------------------------------
// Layer 2: out = zagg + relu(bn(h)) @ W2r^T + b2, log_softmax. 4x M-blocked.
// ---------------------------------------------------------------------------
__global__ __launch_bounds__(128, 2) void gemm2_mfma(const ushort_t* __restrict__ hin,
                                                     const float* __restrict__ scl,
                                                     const float* __restrict__ sh,
                                                     const ushort_t* __restrict__ zagg,
                                                     const ushort_t* __restrict__ Wb2r,
                                                     const float* __restrict__ b2l,
                                                     float* __restrict__ out) {
  int w = threadIdx.x >> 6;
  int l = threadIdx.x & 63;
  int m = l & 15;
  int q = l >> 4;
  int rowblk = blockIdx.x * 128 + w * 64;
  int rl[4];
#pragma unroll
  for (int mt = 0; mt < 4; mt++) {
    int row = rowblk + mt * 16 + m;
    rl[mt] = row < NN ? row : NN - 1;
  }
  f32x4 acc[4][4];
#pragma unroll
  for (int mt = 0; mt < 4; mt++)
#pragma unroll
    for (int t = 0; t < 4; t++) acc[mt][t] = (f32x4){0.f, 0.f, 0.f, 0.f};
#pragma unroll
  for (int ks = 0; ks < 4; ks++) {
    int k0 = ks * 32 + q * 8;
    float4 s0 = ((const float4*)(scl + k0))[0];
    float4 s1 = ((const float4*)(scl + k0))[1];
    float4 h0 = ((const float4*)(sh + k0))[0];
    float4 h1 = ((const float4*)(sh + k0))[1];
    bf16x8 bfr[4];
#pragma unroll
    for (int t = 0; t < 4; t++)
      bfr[t] = *(const bf16x8*)(Wb2r + (size_t)(t * 16 + m) * DH + k0);
#pragma unroll
    for (int mt = 0; mt < 4; mt++) {
      bf16x8 hv = *(const bf16x8*)(hin + (size_t)rl[mt] * DH + k0);
      bf16x8 af = bn_frag2(hv, s0, s1, h0, h1);
#pragma unroll
      for (int t = 0; t < 4; t++)
        acc[mt][t] = __builtin_amdgcn_mfma_f32_16x16x32_bf16(af, bfr[t], acc[mt][t], 0, 0, 0);
    }
  }
#pragma unroll
  for (int mt = 0; mt < 4; mt++) {
    float v[4][4];
#pragma unroll
    for (int t = 0; t < 4; t++) {
      float bias = b2l[t * 16 + m];
#pragma unroll
      for (int r = 0; r < 4; r++) {
        int rr = rowblk + mt * 16 + q * 4 + r;
        float zg = (rr < NN) ? bf2f((short)zagg[(size_t)rr * DOUT + t * 16 + m]) : 0.f;
        v[t][r] = acc[mt][t][r] + zg + bias;
      }
    }
#pragma unroll
    for (int r = 0; r < 4; r++) {
      float mx = fmaxf(fmaxf(v[0][r], v[1][r]), fmaxf(v[2][r], v[3][r]));
      mx = fmaxf(mx, __shfl_xor(mx, 1, 64));
      mx = fmaxf(mx, __shfl_xor(mx, 2, 64));
      mx = fmaxf(mx, __shfl_xor(mx, 4, 64));
      mx = fmaxf(mx, __shfl_xor(mx, 8, 64));
      float se = __expf(v[0][r] - mx) + __expf(v[1][r] - mx) +
                 __expf(v[2][r] - mx) + __expf(v[3][r] - mx);
      se += __shfl_xor(se, 1, 64);
      se += __shfl_xor(se, 2, 64);
      se += __shfl_xor(se, 4, 64);
      se += __shfl_xor(se, 8, 64);
      float lse = mx + logf(se);
      int rr = rowblk + mt * 16 + q * 4 + r;
      if (rr < NN) {
#pragma unroll
        for (int t = 0; t < 4; t++)
          out[(size_t)rr * DOUT + t * 16 + m] = v[t][r] - lse;
      }
    }
  }
}

// ---------------------------------------------------------------------------
extern "C" void kernel_launch(void* const* d_in, const int* in_sizes, int n_in,
                              void* d_out, int out_size, void* d_ws, size_t ws_size,
                              hipStream_t stream) {
  const float* x = (const float*)d_in[0];
  const int* ei = (const int*)d_in[1];
  const float* W1l = (const float*)d_in[2];
  const float* b1l = (const float*)d_in[3];
  const float* W1r = (const float*)d_in[4];
  const float* gamma = (const float*)d_in[5];
  const float* beta = (const float*)d_in[6];
  const float* W2l = (const float*)d_in[7];
  const float* b2l = (const float*)d_in[8];
  const float* W2r = (const float*)d_in[9];
  float* out = (float*)d_out;
  int E = in_sizes[1] / 2;
  int nblkg = (NN + 127) / 128;

  // workspace (~110 MB):
  //   u0 (25.6 MB): edges int2[E] (first half) + q int2[E] (second half);
  //     later reused as z_bf16[N*64] (overlaps edges, dead after bin) +
  //     zagg_bf16[N*64] (overlaps q, dead after fill).
  //   x_bf16 | s_bf16 | h_bf16 | degi | row_ptr | col | stats | qmeta | W
  char* p = (char*)d_ws;
  int2* edges = (int2*)p;
  ushort_t* z_bf = (ushort_t*)p;
  int2* q = (int2*)(p + (size_t)NN * DOUT * sizeof(ushort_t));
  ushort_t* zagg_bf = z_bf + (size_t)NN * DOUT;
  p += (size_t)NN * DOUT * 2 * sizeof(ushort_t);
  ushort_t* x_bf = (ushort_t*)p;  p += (size_t)NN * DH * sizeof(ushort_t);
  ushort_t* s_bf = (ushort_t*)p;  p += (size_t)NN * DH * sizeof(ushort_t);
  ushort_t* h_bf = (ushort_t*)p;  p += (size_t)NN * DH * sizeof(ushort_t);
  int* degi = (int*)p;            p += NN * sizeof(int);
  int* row_ptr = (int*)p;         p += NN * sizeof(int);
  int* col = (int*)p;             p += (size_t)E * sizeof(int);
  float* sums = (float*)p;        p += DH * sizeof(float);
  float* sumsq = (float*)p;       p += DH * sizeof(float);
  float* scl = (float*)p;         p += DH * sizeof(float);
  float* sh = (float*)p;          p += DH * sizeof(float);
  int* flag = (int*)p;            p += 4 * sizeof(int);
  int* qbase = (int*)p;           p += (NWIN + 4) * sizeof(int);
  int* qcur = (int*)p;            p += NWIN * sizeof(int);
  ushort_t* Wb1 = (ushort_t*)p;   p += 128 * 256 * sizeof(ushort_t);
  ushort_t* Wb2l = (ushort_t*)p;  p += 64 * 128 * sizeof(ushort_t);
  ushort_t* Wb2r = (ushort_t*)p;

  hipMemsetAsync(degi, 0, NN * sizeof(int), stream);
  hipMemsetAsync(sums, 0, 2 * DH * sizeof(float), stream);

  detect_kernel<<<1, 256, 0, stream>>>(ei, E, flag);
  convw_kernel<<<192, 256, 0, stream>>>(W1l, W1r, W2l, W2r, Wb1, Wb2l, Wb2r);
  convx_kernel<<<(NN * DH / 8 + 255) / 256, 256, 0, stream>>>(x, x_bf);
  convert_deg_kernel<<<(E + 255) / 256, 256, 0, stream>>>(ei, E, flag, edges, degi);
  scan_kernel<<<1, 1024, 0, stream>>>(degi, row_ptr);
  qinit_kernel<<<1, 256, 0, stream>>>(row_ptr, E, qbase, qcur);
  bin_kernel<<<(E + BIN_EPB - 1) / BIN_EPB, 256, 0, stream>>>(edges, E, qcur, q);
  fill_kernel<<<NWIN, 512, 0, stream>>>(q, qbase, row_ptr, col);
  gather128_kernel<<<(NN * 16 + 255) / 256, 256, 0, stream>>>(x_bf, col, row_ptr, degi, s_bf);
  gemm1_mfma<<<nblkg, 128, 0, stream>>>(s_bf, x_bf, Wb1, b1l, h_bf, sums, sumsq);
  bn_prep_kernel<<<1, 128, 0, stream>>>(sums, sumsq, gamma, beta, scl, sh);
  z_mfma<<<nblkg, 128, 0, stream>>>(h_bf, scl, sh, Wb2l, z_bf);
  gather64_kernel<<<(NN * 8 + 255) / 256, 256, 0, stream>>>(z_bf, col, row_ptr, degi, zagg_bf);
  gemm2_mfma<<<nblkg, 128, 0, stream>>>(h_bf, scl, sh, zagg_bf, Wb2r, b2l, out);
}